// Round 23
// baseline (238.714 us; speedup 1.0000x reference)
//
#include <hip/hip_runtime.h>

#define L_SEQ 512
#define BATCH 2
#define NROWS (BATCH*L_SEQ)   // 1024
#define DMODEL 512
#define DINNER 1024
#define DSTATE 128
#define NHEADSM 16
#define CONVD 1280
#define DINPROJ 2320
#define QCH 32
#define NCH 16
#define WI_PAD 2368           // 2320 padded to x64
#define WH_PAD 1024           // 1000 padded to x64

// ws float offsets (after 256B header holding the dtype flag)
#define W_CONVW 0
#define W_CONVB 10240
#define W_DTB   12800
#define W_ALOG  12832
#define W_DD    12864
#define W_RMSW  12896
#define W_LNW   14944
#define W_LNB   15968
#define W_HEADB 16992
#define O_X     18048
#define O_ZX    (O_X  + NROWS*DMODEL)      // ZX bf16 (over-alloc'd)
#define O_XC    (O_ZX + NROWS*DINPROJ)     // conv'd B/C, bf16 [NROWS][256] (over-alloc'd)
#define O_DT    (O_XC + NROWS*256)
#define O_Y     (O_DT + NROWS*NHEADSM)     // intra-chunk Y, bf16 (over-alloc'd)
#define O_O     (O_Y  + NROWS*DINNER)      // out_proj output, bf16 (over-alloc'd)
#define O_LA    (O_O  + NROWS*DMODEL)
#define O_SS    (O_LA + 16384)             // per-row sum(g^2), NROWS floats
#define O_S     (O_SS + 1024)              // S states, bf16 (over-alloc'd)
#define O_UB    (O_S  + 4194304)
// ushort offsets within bf16 region:
#define U_WI   0
#define U_WO   2424832
#define U_WH   3473408
#define U_XBF  3997696
#define U_YBF  4521984

#define NPREPW (2*WI_PAD + 2*DMODEL + WH_PAD)   // 6848 weight rows

typedef __attribute__((ext_vector_type(8))) short short8;
typedef __attribute__((ext_vector_type(4))) float floatx4;

__device__ __forceinline__ float b2f(unsigned short h){ return __uint_as_float(((unsigned)h)<<16); }
__device__ __forceinline__ unsigned short f2b(float x){
  unsigned u = __float_as_uint(x);
  return (unsigned short)((u + 0x7fffu + ((u>>16)&1u)) >> 16);
}
__device__ __forceinline__ float loadIn(const void* p, long i, int f){
  return f ? b2f(((const unsigned short*)p)[i]) : ((const float*)p)[i];
}

// async global->LDS direct copy, 16B per lane (wave-uniform dest + lane*16).
__device__ __forceinline__ void gload16(const void* g, void* l){
  __builtin_amdgcn_global_load_lds((const __attribute__((address_space(1))) void*)g,
                                   (__attribute__((address_space(3))) void*)l, 16, 0, 0);
}

// ---- dtype detect ----
__global__ void k_detect(const unsigned* __restrict__ emb, int* __restrict__ flag){
  __shared__ int red[256];
  int t = threadIdx.x; int cnt = 0;
  for (int i = 0; i < 16; i++){
    unsigned w = emb[t*16 + i];
    unsigned e = (w >> 7) & 0xffu;
    cnt += (e >= 100 && e <= 126) ? 1 : 0;
  }
  red[t] = cnt; __syncthreads();
  if (t == 0){
    int s = 0;
    for (int i = 0; i < 256; i++) s += red[i];
    *flag = (s > 2048) ? 1 : 0;
  }
}

struct ConvArgs { const void* src[9]; int off[10]; };

// fused startup: small-param convert + weight bf16 prep + embedding.
// WoB rows are PRE-SCALED by rms weight rw: Wo'[n,k] = Wo[n,k]*rw[k]  (R7, verified)
__global__ void k_prep(ConvArgs a, const void* __restrict__ wi, const void* __restrict__ wo,
                       const void* __restrict__ wh, const void* __restrict__ rwsrc,
                       const int* __restrict__ tok,
                       const void* __restrict__ emb, const int* __restrict__ flag,
                       float* __restrict__ dstSmall,
                       unsigned short* __restrict__ WiB, unsigned short* __restrict__ WoB,
                       unsigned short* __restrict__ WhB,
                       float* __restrict__ x, unsigned short* __restrict__ xbf)
{
  int f = *flag;
  int blk = blockIdx.x;
  if (blk < 71){
    int i = blk*256 + threadIdx.x;
    if (i < a.off[9]){
      int s = 0;
      while (i >= a.off[s+1]) s++;
      dstSmall[i] = loadIn(a.src[s], i - a.off[s], f);
    }
    return;
  }
  blk -= 71;
  if (blk < NPREPW){
    int r = blk;
    if (r < 2*WI_PAD){
      int layer = r / WI_PAD, row = r % WI_PAD;
      long db = ((long)layer*WI_PAD + row)*DMODEL;
      if (row < DINPROJ){
        long sb = ((long)layer*DINPROJ + row)*DMODEL;
        for (int c = threadIdx.x; c < DMODEL; c += 256)
          WiB[db + c] = f ? ((const unsigned short*)wi)[sb + c] : f2b(((const float*)wi)[sb + c]);
      } else {
        for (int c = threadIdx.x; c < DMODEL; c += 256) WiB[db + c] = 0;
      }
    } else if (r < 2*WI_PAD + 2*DMODEL){
      int rr = r - 2*WI_PAD;
      int layer = rr >> 9;                 // 512 rows per layer
      long db = (long)rr*DINNER;
      for (int c = threadIdx.x; c < DINNER; c += 256){
        float wv = loadIn(wo, db + c, f);
        float rv = loadIn(rwsrc, (long)layer*DINNER + c, f);
        WoB[db + c] = f2b(wv * rv);
      }
    } else {
      int row = r - 2*WI_PAD - 2*DMODEL;
      long db = (long)row*DMODEL;
      if (row < 1000){
        for (int c = threadIdx.x; c < DMODEL; c += 256)
          WhB[db + c] = f ? ((const unsigned short*)wh)[db + c] : f2b(((const float*)wh)[db + c]);
      } else {
        for (int c = threadIdx.x; c < DMODEL; c += 256) WhB[db + c] = 0;
      }
    }
    return;
  }
  int r = blk - NPREPW;   // embed row
  long base = (long)tok[r] * DMODEL;
  for (int c = threadIdx.x; c < DMODEL; c += 256){
    float v = loadIn(emb, base + c, f);
    x[(long)r*DMODEL + c] = v;
    xbf[(long)r*DMODEL + c] = f ? ((const unsigned short*)emb)[base + c] : f2b(v);
  }
}

// ======== bf16 MFMA GEMM: C[M,N] = A[M,K] @ B[N,K]^T (+bias, +row rms-scale) ========
// outMode: 0 = f32 out; 1 = bf16 iff input flag set (head output); 2 = always bf16.
template<int BM, int BN>
__global__ __launch_bounds__(256) void k_mfma_nt(
    const unsigned short* __restrict__ A, const unsigned short* __restrict__ B,
    void* __restrict__ C, int M, int N, int K,
    const float* __restrict__ bias, const float* __restrict__ rowscale,
    const int* __restrict__ flag, int outMode)
{
  constexpr int MI = BM/32;
  constexpr int NI = BN/32;
  constexpr int CA = BM/32;
  constexpr int CB = BN/32;
  __shared__ __align__(16) unsigned short As[2][BM*64];
  __shared__ __align__(16) unsigned short Bs[2][BN*64];
  int f = *flag;
  int t = threadIdx.x;
  int w = t >> 6, lane = t & 63;
  int quad = lane >> 4, l16 = lane & 15;
  int m0 = blockIdx.y * BM, n0 = blockIdx.x * BN;
  int wm = (w & 1) * (BM/2), wn = (w >> 1) * (BN/2);
  floatx4 acc[MI][NI];
  #pragma unroll
  for (int mi = 0; mi < MI; mi++)
    #pragma unroll
    for (int ni = 0; ni < NI; ni++) acc[mi][ni] = (floatx4){0.f,0.f,0.f,0.f};

  const char* Ag = (const char*)A;
  const char* Bg = (const char*)B;
  long aOff[CA]; int aL[CA];
  #pragma unroll
  for (int j = 0; j < CA; j++){
    int i = (w*CA + j)*64 + lane;
    int r = i >> 3, g = (i & 7) ^ (r & 7);
    aOff[j] = ((long)(m0 + r)*K + g*8)*2;
    aL[j] = (w*CA + j)*1024;
  }
  long bOff[CB]; int bL[CB];
  #pragma unroll
  for (int j = 0; j < CB; j++){
    int i = (w*CB + j)*64 + lane;
    int r = i >> 3, g = (i & 7) ^ (r & 7);
    bOff[j] = ((long)(n0 + r)*K + g*8)*2;
    bL[j] = (w*CB + j)*1024;
  }

  const int NKI = K >> 6;
  #pragma unroll
  for (int j = 0; j < CA; j++) gload16(Ag + aOff[j], (char*)As[0] + aL[j]);
  #pragma unroll
  for (int j = 0; j < CB; j++) gload16(Bg + bOff[j], (char*)Bs[0] + bL[j]);
  asm volatile("s_waitcnt vmcnt(0)" ::: "memory");
  __syncthreads();

  for (int ki = 0; ki < NKI; ki++){
    int cur = ki & 1;
    if (ki + 1 < NKI){
      long kb = (long)(ki + 1)*128;
      #pragma unroll
      for (int j = 0; j < CA; j++) gload16(Ag + aOff[j] + kb, (char*)As[cur^1] + aL[j]);
      #pragma unroll
      for (int j = 0; j < CB; j++) gload16(Bg + bOff[j] + kb, (char*)Bs[cur^1] + bL[j]);
    }
    const unsigned short* Ac = As[cur];
    const unsigned short* Bc = Bs[cur];
    #pragma unroll
    for (int ks = 0; ks < 2; ks++){
      short8 af[MI], bfr[NI];
      #pragma unroll
      for (int mi = 0; mi < MI; mi++){
        int r = wm + mi*16 + l16;
        int pos = ((ks << 2) + quad) ^ (r & 7);
        af[mi] = *(const short8*)&Ac[r*64 + pos*8];
      }
      #pragma unroll
      for (int ni = 0; ni < NI; ni++){
        int r = wn + ni*16 + l16;
        int pos = ((ks << 2) + quad) ^ (r & 7);
        bfr[ni] = *(const short8*)&Bc[r*64 + pos*8];
      }
      #pragma unroll
      for (int mi = 0; mi < MI; mi++)
        #pragma unroll
        for (int ni = 0; ni < NI; ni++)
          acc[mi][ni] = __builtin_amdgcn_mfma_f32_16x16x32_bf16(af[mi], bfr[ni], acc[mi][ni], 0, 0, 0);
    }
    asm volatile("s_waitcnt vmcnt(0)" ::: "memory");
    __syncthreads();
  }
  #pragma unroll
  for (int mi = 0; mi < MI; mi++)
    #pragma unroll
    for (int ni = 0; ni < NI; ni++){
      int col = n0 + wn + ni*16 + l16;
      if (col >= N) continue;
      float bv = bias ? bias[col] : 0.f;
      #pragma unroll
      for (int rr = 0; rr < 4; rr++){
        int row = m0 + wm + mi*16 + (quad << 2) + rr;
        float v = acc[mi][ni][rr] + bv;
        if (rowscale) v *= rsqrtf(rowscale[row]*(1.f/(float)DINNER) + 1e-5f);
        long idx = (long)row*N + col;
        if (outMode == 2 || (outMode == 1 && f)) ((unsigned short*)C)[idx] = f2b(v);
        else                                     ((float*)C)[idx] = v;
      }
    }
}

// conv+silu for the shared B/C channels (256 of 1280, bf16 in/out) + dt softplus.
__global__ __launch_bounds__(256) void k_conv_dt(
    const unsigned short* __restrict__ zx, const float* __restrict__ cw, const float* __restrict__ cb,
    const float* __restrict__ dtb, unsigned short* __restrict__ xc, float* __restrict__ dt)
{
  int r = blockIdx.x; int b = r >> 9, l = r & 511;
  int t = threadIdx.x;
  {
    int ch = 1024 + t;                       // channel in [1024,1280)
    float s = cb[ch];
    #pragma unroll
    for (int k = 0; k < 4; k++){
      int pos = l - 3 + k;
      if (pos >= 0)
        s = fmaf(b2f(zx[(long)(b*L_SEQ + pos)*DINPROJ + 2048 + t]), cw[ch*4 + k], s);
    }
    xc[(long)r*256 + t] = f2b(s / (1.f + __expf(-s)));   // silu, bf16
  }
  if (t < NHEADSM){
    float v = b2f(zx[(long)r*DINPROJ + DINNER + CONVD + t]) + dtb[t];
    dt[r*NHEADSM + t] = (v > 20.f) ? v : log1pf(__expf(v));  // softplus
  }
}

// ================= chunked SSD scan (MFMA), x-conv fused =================
// ZX/XC/Y/S all bf16 (R15/R17/R21 verified).
__global__ __launch_bounds__(256) void k_chunk1(
    const unsigned short* __restrict__ zx, const unsigned short* __restrict__ xc,
    const float* __restrict__ dtbuf,
    const float* __restrict__ alog, const float* __restrict__ dvec,
    const float* __restrict__ cw, const float* __restrict__ cb,
    unsigned short* __restrict__ S, float* __restrict__ LAb,
    unsigned short* __restrict__ y)
{
  int c = blockIdx.x, h = blockIdx.y, b = blockIdx.z;
  int t = threadIdx.x, w = t >> 6, lane = t & 63;
  int quad = lane >> 4, l16 = lane & 15;
  int l0 = c*QCH;
  __shared__ unsigned short XT[64*40];    // XT[p][j] = X[j][p]
  __shared__ union {                      // time-multiplexed
    float xs[35*64];                      // x conv input slab (f32 in LDS)
    unsigned short BTc[128*40];           // BTc[n][j] = coef[j]*B[j][n]
  } U;
  __shared__ unsigned short Bb[32*136];   // B[j][n]
  __shared__ unsigned short Cb[32*136];   // C[i][n]
  __shared__ unsigned short Gb[32*40];    // G[i][j]
  __shared__ float dtl[32], lal[32], coef[32];
  float A  = -__expf(alog[h]);
  float Dv = dvec[h];

  // stage raw x conv input: rows l0-3..l0+31, zx cols 1024+h*64 .. +64
  for (int idx = t; idx < 35*64; idx += 256){
    int jr = idx >> 6, cc = idx & 63;
    int l = l0 - 3 + jr;
    U.xs[idx] = (l >= 0) ? b2f(zx[(long)(b*L_SEQ + l)*DINPROJ + 1024 + h*64 + cc]) : 0.f;
  }
  // B/C (conv'd by k_conv_dt, bf16 [r][256]) -> regs (raw ushort)
  unsigned short bu[16], cu[16];
  #pragma unroll
  for (int k = 0; k < 16; k++){
    int idx = t + k*256; int j = idx >> 7, n = idx & 127;
    long rb = (long)(b*L_SEQ + l0 + j)*256;
    bu[k] = xc[rb + n];
    cu[k] = xc[rb + 128 + n];
  }
  // lane-parallel inclusive prefix over dt
  if (t < 32){
    float d = dtbuf[(b*L_SEQ + l0 + t)*NHEADSM + h];
    dtl[t] = d;
    float s = d;
    #pragma unroll
    for (int o = 1; o < 32; o <<= 1){
      float u = __shfl_up(s, o, 32);
      if (t >= o) s += u;
    }
    float la = s * A;
    lal[t] = la;
    float tot = __shfl(s, 31, 32) * A;
    coef[t] = __expf(tot - la) * d;
    LAb[(b*NHEADSM + h)*L_SEQ + l0 + t] = la;
  }
  __syncthreads();     // xs staged, coef ready
  // conv+silu for x (identical tap order/padding semantics to reference)
  float xv[8];
  #pragma unroll
  for (int k = 0; k < 8; k++){
    int idx = t + k*256; int j = idx >> 6, p = idx & 63;
    int ch = h*64 + p;
    float s0 = cb[ch];
    #pragma unroll
    for (int kk = 0; kk < 4; kk++)
      s0 = fmaf(U.xs[(j + kk)*64 + p], cw[ch*4 + kk], s0);
    xv[k] = s0 / (1.f + __expf(-s0));
  }
  __syncthreads();     // xs dead; BTc may be written
  #pragma unroll
  for (int k = 0; k < 8; k++){
    int idx = t + k*256; int j = idx >> 6, p = idx & 63;
    XT[p*40 + j] = f2b(xv[k]);
  }
  #pragma unroll
  for (int k = 0; k < 16; k++){
    int idx = t + k*256; int j = idx >> 7, n = idx & 127;
    Bb[j*136 + n] = bu[k];
    Cb[j*136 + n] = cu[k];
    U.BTc[n*40 + j] = f2b(b2f(bu[k]) * coef[j]);
  }
  __syncthreads();

  short8 afS = *(const short8*)&XT[(w*16 + l16)*40 + quad*8];
  floatx4 accS[8];
  #pragma unroll
  for (int nb = 0; nb < 8; nb++){
    short8 bfS = *(const short8*)&U.BTc[(nb*16 + l16)*40 + quad*8];
    accS[nb] = __builtin_amdgcn_mfma_f32_16x16x32_bf16(afS, bfS, (floatx4){0.f,0.f,0.f,0.f}, 0, 0, 0);
  }
  int ti = w & 1, tj = w >> 1;
  floatx4 accG = (floatx4){0.f,0.f,0.f,0.f};
  #pragma unroll
  for (int ks = 0; ks < 4; ks++){
    short8 ga = *(const short8*)&Cb[(ti*16 + l16)*136 + ks*32 + quad*8];
    short8 gb = *(const short8*)&Bb[(tj*16 + l16)*136 + ks*32 + quad*8];
    accG = __builtin_amdgcn_mfma_f32_16x16x32_bf16(ga, gb, accG, 0, 0, 0);
  }
  long sb = ((long)((b*NHEADSM + h)*NCH + c))*8192;
  #pragma unroll
  for (int nb = 0; nb < 8; nb++)
    #pragma unroll
    for (int rr = 0; rr < 4; rr++)
      S[sb + (w*16 + quad*4 + rr)*128 + nb*16 + l16] = f2b(accS[nb][rr]);
  #pragma unroll
  for (int rr = 0; rr < 4; rr++){
    int i = ti*16 + quad*4 + rr, j = tj*16 + l16;
    float g = (j <= i) ? __expf(lal[i] - lal[j]) * dtl[j] * accG[rr] : 0.f;
    Gb[i*40 + j] = f2b(g);
  }
  __syncthreads();
  short8 ag = *(const short8*)&Gb[(ti*16 + l16)*40 + quad*8];
  #pragma unroll
  for (int s = 0; s < 2; s++){
    int pb = (w >> 1)*2 + s;
    short8 bx = *(const short8*)&XT[(pb*16 + l16)*40 + quad*8];
    floatx4 accY = __builtin_amdgcn_mfma_f32_16x16x32_bf16(ag, bx, (floatx4){0.f,0.f,0.f,0.f}, 0, 0, 0);
    #pragma unroll
    for (int rr = 0; rr < 4; rr++){
      int i = ti*16 + quad*4 + rr, p = pb*16 + l16;
      float xval = b2f(XT[p*40 + i]);
      y[(long)(b*L_SEQ + l0 + i)*DINNER + h*64 + p] = f2b(fmaf(Dv, xval, accY[rr]));
    }
  }
}

// chunk2: state propagation IN-PLACE over bf16 S (scan carried in f32 regs)
// + zero the SS accumulator.
__global__ __launch_bounds__(256) void k_chunk2(
    unsigned short* __restrict__ S, const float* __restrict__ LAb, float* __restrict__ SS)
{
  if (threadIdx.x == 0) SS[blockIdx.x] = 0.f;
  int bh = blockIdx.x >> 5;
  int e = ((blockIdx.x & 31) << 8) + threadIdx.x;
  long base = (long)bh*NCH*8192 + e;
  int laBase = bh*L_SEQ;
  float lam[NCH];
  #pragma unroll
  for (int c = 0; c < NCH; c++) lam[c] = __expf(LAb[laBase + c*QCH + QCH - 1]);
  float hr = 0.f;
  #pragma unroll
  for (int c = 0; c < NCH; c++){
    long off = base + (long)c*8192;
    float sv = b2f(S[off]);
    S[off] = f2b(hr);
    hr = fmaf(hr, lam[c], sv);
  }
}

// chunk3: yfin = b2f(y) + exp(la_i)*C.H^T with single-bf16 H;
// g = yfin*silu(b2f(z)) -> Ybf once; per-row sum(g^2) atomically into SS.
__global__ __launch_bounds__(256) void k_chunk3(
    const unsigned short* __restrict__ xc, const unsigned short* __restrict__ H,
    const float* __restrict__ LAb, const unsigned short* __restrict__ y,
    const unsigned short* __restrict__ zx, unsigned short* __restrict__ ybf,
    float* __restrict__ SS)
{
  int c = blockIdx.x, h = blockIdx.y, b = blockIdx.z;
  int t = threadIdx.x, w = t >> 6, lane = t & 63;
  int quad = lane >> 4, l16 = lane & 15;
  int l0 = c*QCH;
  __shared__ unsigned short Cb[32*136];
  __shared__ unsigned short Hb[64*136];
  __shared__ float el[32];
  if (t < 32) el[t] = __expf(LAb[(b*NHEADSM + h)*L_SEQ + l0 + t]);
  #pragma unroll
  for (int k = 0; k < 16; k++){
    int idx = t + k*256; int j = idx >> 7, n = idx & 127;
    Cb[j*136 + n] = xc[(long)(b*L_SEQ + l0 + j)*256 + 128 + n];
  }
  long hb = ((long)((b*NHEADSM + h)*NCH + c))*8192;
  #pragma unroll
  for (int k = 0; k < 32; k++){
    int idx = t + k*256; int p = idx >> 7, n = idx & 127;
    Hb[p*136 + n] = H[hb + idx];
  }
  __syncthreads();
  int ti = w & 1;
  float gsq[4] = {0.f, 0.f, 0.f, 0.f};
  #pragma unroll
  for (int s = 0; s < 2; s++){
    int pb = (w >> 1)*2 + s;
    floatx4 acc = (floatx4){0.f,0.f,0.f,0.f};
    #pragma unroll
    for (int ks = 0; ks < 4; ks++){
      short8 a  = *(const short8*)&Cb[(ti*16 + l16)*136 + ks*32 + quad*8];
      short8 hf = *(const short8*)&Hb[(pb*16 + l16)*136 + ks*32 + quad*8];
      acc = __builtin_amdgcn_mfma_f32_16x16x32_bf16(a, hf, acc, 0, 0, 0);
    }
    #pragma unroll
    for (int rr = 0; rr < 4; rr++){
      int i = ti*16 + quad*4 + rr, p = pb*16 + l16;
      long row = (long)(b*L_SEQ + l0 + i);
      long yb = row*DINNER + h*64 + p;
      float yfin = fmaf(el[i], acc[rr], b2f(y[yb]));
      float z = b2f(zx[row*DINPROJ + h*64 + p]);
      float gz = z / (1.f + __expf(-z));
      float g = yfin * gz;
      ybf[yb] = f2b(g);
      gsq[rr] = fmaf(g, g, gsq[rr]);
    }
  }
  // reduce over the 16 lanes sharing each row (same quad, varying l16)
  #pragma unroll
  for (int rr = 0; rr < 4; rr++){
    float v = gsq[rr];
    v += __shfl_xor(v, 1);
    v += __shfl_xor(v, 2);
    v += __shfl_xor(v, 4);
    v += __shfl_xor(v, 8);
    if (l16 == 0)
      atomicAdd(&SS[b*L_SEQ + l0 + ti*16 + quad*4 + rr], v);
  }
}

// add + layernorm; o (out_proj output) now bf16.
__global__ __launch_bounds__(256) void k_add_ln(
    float* __restrict__ x, const unsigned short* __restrict__ o,
    const float* __restrict__ lw, const float* __restrict__ lb,
    unsigned short* __restrict__ xbf)
{
  int r = blockIdx.x, t = threadIdx.x;
  float v[2]; float sm = 0.f;
  #pragma unroll
  for (int i = 0; i < 2; i++){ int c = t + i*256; v[i] = x[(long)r*DMODEL + c] + b2f(o[(long)r*DMODEL + c]); sm += v[i]; }
  #pragma unroll
  for (int off = 1; off < 64; off <<= 1) sm += __shfl_xor(sm, off);
  __shared__ float red[4]; __shared__ float red2[4];
  int w = t >> 6, lane = t & 63;
  if (lane == 0) red[w] = sm;
  __syncthreads();
  float mu = (red[0] + red[1] + red[2] + red[3]) / (float)DMODEL;
  float var = 0.f;
  #pragma unroll
  for (int i = 0; i < 2; i++){ v[i] -= mu; var = fmaf(v[i], v[i], var); }
  #pragma unroll
  for (int off = 1; off < 64; off <<= 1) var += __shfl_xor(var, off);
  if (lane == 0) red2[w] = var;
  __syncthreads();
  float vv = (red2[0] + red2[1] + red2[2] + red2[3]) / (float)DMODEL;
  float sc = rsqrtf(vv + 1e-5f);
  #pragma unroll
  for (int i = 0; i < 2; i++){
    int c = t + i*256;
    float ov = v[i]*sc*lw[c] + lb[c];
    x[(long)r*DMODEL + c] = ov;
    xbf[(long)r*DMODEL + c] = f2b(ov);
  }
}

extern "C" void kernel_launch(void* const* d_in, const int* in_sizes, int n_in,
                              void* d_out, int out_size, void* d_ws, size_t ws_size,
                              hipStream_t stream)
{
  const int* tokens = (const int*)d_in[0];
  const void* emb = d_in[1];
  int* flag = (int*)d_ws;
  float* ws = (float*)((char*)d_ws + 256);

  k_detect<<<1, 256, 0, stream>>>((const unsigned*)emb, flag);

  ConvArgs ca;
  const int sizes[9] = {10240, 2560, 32, 32, 32, 2048, 1024, 1024, 1000};
  const int idxs[9]  = {3, 4, 5, 6, 7, 8, 10, 11, 13};
  int off = 0;
  for (int s = 0; s < 9; s++){ ca.src[s] = d_in[idxs[s]]; ca.off[s] = off; off += sizes[s]; }
  ca.off[9] = off;

  float* X  = ws + O_X;
  unsigned short* ZXu = (unsigned short*)(ws + O_ZX);
  unsigned short* XCu = (unsigned short*)(ws + O_XC);
  float* DT = ws + O_DT;
  unsigned short* Y16 = (unsigned short*)(ws + O_Y);
  unsigned short* Obu = (unsigned short*)(ws + O_O);
  float* LA = ws + O_LA;
  float* SSb= ws + O_SS;
  unsigned short* S16 = (unsigned short*)(ws + O_S);
  unsigned short* ub  = (unsigned short*)(ws + O_UB);
  unsigned short* WiB = ub + U_WI;
  unsigned short* WoB = ub + U_WO;
  unsigned short* WhB = ub + U_WH;
  unsigned short* Xbf = ub + U_XBF;
  unsigned short* Ybf = ub + U_YBF;

  k_prep<<<71 + NPREPW + NROWS, 256, 0, stream>>>(
      ca, d_in[2], d_in[9], d_in[12], d_in[8], tokens, emb, flag,
      ws, WiB, WoB, WhB, X, Xbf);

  for (int layer = 0; layer < 2; layer++){
    // in_proj: ZX output stored bf16 (outMode=2)
    k_mfma_nt<32,64><<<dim3(WI_PAD/64, NROWS/32), 256, 0, stream>>>(
        Xbf, WiB + (long)layer*WI_PAD*DMODEL, (void*)ZXu,
        NROWS, DINPROJ, DMODEL, (const float*)nullptr, (const float*)nullptr, flag, 2);
    k_conv_dt<<<NROWS, 256, 0, stream>>>(
        ZXu, ws + W_CONVW + layer*5120, ws + W_CONVB + layer*1280, ws + W_DTB + layer*16, XCu, DT);
    k_chunk1<<<dim3(NCH, NHEADSM, BATCH), 256, 0, stream>>>(
        ZXu, XCu, DT, ws + W_ALOG + layer*16, ws + W_DD + layer*16,
        ws + W_CONVW + layer*5120, ws + W_CONVB + layer*1280, S16, LA, Y16);
    k_chunk2<<<1024, 256, 0, stream>>>(S16, LA, SSb);
    k_chunk3<<<dim3(NCH, NHEADSM, BATCH), 256, 0, stream>>>(
        XCu, S16, LA, Y16, ZXu, Ybf, SSb);
    // out_proj: Ob stored bf16 (outMode=2), rms row-scale in epilogue
    k_mfma_nt<32,32><<<dim3(DMODEL/32, NROWS/32), 256, 0, stream>>>(
        Ybf, WoB + (long)layer*DMODEL*DINNER, (void*)Obu,
        NROWS, DMODEL, DINNER, (const float*)nullptr, SSb, flag, 2);
    k_add_ln<<<NROWS, 256, 0, stream>>>(X, Obu, ws + W_LNW + layer*512, ws + W_LNB + layer*512, Xbf);
  }

  k_mfma_nt<32,64><<<dim3(WH_PAD/64, NROWS/32), 256, 0, stream>>>(
      Xbf, WhB, d_out, NROWS, 1000, DMODEL, ws + W_HEADB, (const float*)nullptr, flag, 1);
}

// Round 24
// 236.727 us; speedup vs baseline: 1.0084x; 1.0084x over previous
//
#include <hip/hip_runtime.h>

#define L_SEQ 512
#define BATCH 2
#define NROWS (BATCH*L_SEQ)   // 1024
#define DMODEL 512
#define DINNER 1024
#define DSTATE 128
#define NHEADSM 16
#define CONVD 1280
#define DINPROJ 2320
#define QCH 32
#define NCH 16
#define WI_PAD 2368           // 2320 padded to x64
#define WH_PAD 1024           // 1000 padded to x64

// ws float offsets (after 256B header holding the dtype flag)
#define W_CONVW 0
#define W_CONVB 10240
#define W_DTB   12800
#define W_ALOG  12832
#define W_DD    12864
#define W_RMSW  12896
#define W_LNW   14944
#define W_LNB   15968
#define W_HEADB 16992
#define O_X     18048
#define O_ZX    (O_X  + NROWS*DMODEL)      // ZX bf16 (over-alloc'd)
#define O_XC    (O_ZX + NROWS*DINPROJ)     // conv'd B/C, bf16 [NROWS][256] (over-alloc'd)
#define O_DT    (O_XC + NROWS*256)
#define O_Y     (O_DT + NROWS*NHEADSM)     // intra-chunk Y, bf16 (over-alloc'd)
#define O_O     (O_Y  + NROWS*DINNER)      // out_proj output, f32 (R21 best-measured)
#define O_LA    (O_O  + NROWS*DMODEL)
#define O_SS    (O_LA + 16384)             // per-row sum(g^2), NROWS floats
#define O_S     (O_SS + 1024)              // S states, bf16 (over-alloc'd)
#define O_UB    (O_S  + 4194304)
// ushort offsets within bf16 region:
#define U_WI   0
#define U_WO   2424832
#define U_WH   3473408
#define U_XBF  3997696
#define U_YBF  4521984

#define NPREPW (2*WI_PAD + 2*DMODEL + WH_PAD)   // 6848 weight rows

typedef __attribute__((ext_vector_type(8))) short short8;
typedef __attribute__((ext_vector_type(4))) float floatx4;

__device__ __forceinline__ float b2f(unsigned short h){ return __uint_as_float(((unsigned)h)<<16); }
__device__ __forceinline__ unsigned short f2b(float x){
  unsigned u = __float_as_uint(x);
  return (unsigned short)((u + 0x7fffu + ((u>>16)&1u)) >> 16);
}
__device__ __forceinline__ float loadIn(const void* p, long i, int f){
  return f ? b2f(((const unsigned short*)p)[i]) : ((const float*)p)[i];
}

// async global->LDS direct copy, 16B per lane (wave-uniform dest + lane*16).
__device__ __forceinline__ void gload16(const void* g, void* l){
  __builtin_amdgcn_global_load_lds((const __attribute__((address_space(1))) void*)g,
                                   (__attribute__((address_space(3))) void*)l, 16, 0, 0);
}

// ---- dtype detect ----
__global__ void k_detect(const unsigned* __restrict__ emb, int* __restrict__ flag){
  __shared__ int red[256];
  int t = threadIdx.x; int cnt = 0;
  for (int i = 0; i < 16; i++){
    unsigned w = emb[t*16 + i];
    unsigned e = (w >> 7) & 0xffu;
    cnt += (e >= 100 && e <= 126) ? 1 : 0;
  }
  red[t] = cnt; __syncthreads();
  if (t == 0){
    int s = 0;
    for (int i = 0; i < 256; i++) s += red[i];
    *flag = (s > 2048) ? 1 : 0;
  }
}

struct ConvArgs { const void* src[9]; int off[10]; };

// fused startup: small-param convert + weight bf16 prep + embedding.
// WoB rows are PRE-SCALED by rms weight rw: Wo'[n,k] = Wo[n,k]*rw[k]  (R7, verified)
__global__ void k_prep(ConvArgs a, const void* __restrict__ wi, const void* __restrict__ wo,
                       const void* __restrict__ wh, const void* __restrict__ rwsrc,
                       const int* __restrict__ tok,
                       const void* __restrict__ emb, const int* __restrict__ flag,
                       float* __restrict__ dstSmall,
                       unsigned short* __restrict__ WiB, unsigned short* __restrict__ WoB,
                       unsigned short* __restrict__ WhB,
                       float* __restrict__ x, unsigned short* __restrict__ xbf)
{
  int f = *flag;
  int blk = blockIdx.x;
  if (blk < 71){
    int i = blk*256 + threadIdx.x;
    if (i < a.off[9]){
      int s = 0;
      while (i >= a.off[s+1]) s++;
      dstSmall[i] = loadIn(a.src[s], i - a.off[s], f);
    }
    return;
  }
  blk -= 71;
  if (blk < NPREPW){
    int r = blk;
    if (r < 2*WI_PAD){
      int layer = r / WI_PAD, row = r % WI_PAD;
      long db = ((long)layer*WI_PAD + row)*DMODEL;
      if (row < DINPROJ){
        long sb = ((long)layer*DINPROJ + row)*DMODEL;
        for (int c = threadIdx.x; c < DMODEL; c += 256)
          WiB[db + c] = f ? ((const unsigned short*)wi)[sb + c] : f2b(((const float*)wi)[sb + c]);
      } else {
        for (int c = threadIdx.x; c < DMODEL; c += 256) WiB[db + c] = 0;
      }
    } else if (r < 2*WI_PAD + 2*DMODEL){
      int rr = r - 2*WI_PAD;
      int layer = rr >> 9;                 // 512 rows per layer
      long db = (long)rr*DINNER;
      for (int c = threadIdx.x; c < DINNER; c += 256){
        float wv = loadIn(wo, db + c, f);
        float rv = loadIn(rwsrc, (long)layer*DINNER + c, f);
        WoB[db + c] = f2b(wv * rv);
      }
    } else {
      int row = r - 2*WI_PAD - 2*DMODEL;
      long db = (long)row*DMODEL;
      if (row < 1000){
        for (int c = threadIdx.x; c < DMODEL; c += 256)
          WhB[db + c] = f ? ((const unsigned short*)wh)[db + c] : f2b(((const float*)wh)[db + c]);
      } else {
        for (int c = threadIdx.x; c < DMODEL; c += 256) WhB[db + c] = 0;
      }
    }
    return;
  }
  int r = blk - NPREPW;   // embed row
  long base = (long)tok[r] * DMODEL;
  for (int c = threadIdx.x; c < DMODEL; c += 256){
    float v = loadIn(emb, base + c, f);
    x[(long)r*DMODEL + c] = v;
    xbf[(long)r*DMODEL + c] = f ? ((const unsigned short*)emb)[base + c] : f2b(v);
  }
}

// ======== bf16 MFMA GEMM: C[M,N] = A[M,K] @ B[N,K]^T (+bias, +row rms-scale) ========
// outMode: 0 = f32 out; 1 = bf16 iff input flag set (head output); 2 = always bf16.
template<int BM, int BN>
__global__ __launch_bounds__(256) void k_mfma_nt(
    const unsigned short* __restrict__ A, const unsigned short* __restrict__ B,
    void* __restrict__ C, int M, int N, int K,
    const float* __restrict__ bias, const float* __restrict__ rowscale,
    const int* __restrict__ flag, int outMode)
{
  constexpr int MI = BM/32;
  constexpr int NI = BN/32;
  constexpr int CA = BM/32;
  constexpr int CB = BN/32;
  __shared__ __align__(16) unsigned short As[2][BM*64];
  __shared__ __align__(16) unsigned short Bs[2][BN*64];
  int f = *flag;
  int t = threadIdx.x;
  int w = t >> 6, lane = t & 63;
  int quad = lane >> 4, l16 = lane & 15;
  int m0 = blockIdx.y * BM, n0 = blockIdx.x * BN;
  int wm = (w & 1) * (BM/2), wn = (w >> 1) * (BN/2);
  floatx4 acc[MI][NI];
  #pragma unroll
  for (int mi = 0; mi < MI; mi++)
    #pragma unroll
    for (int ni = 0; ni < NI; ni++) acc[mi][ni] = (floatx4){0.f,0.f,0.f,0.f};

  const char* Ag = (const char*)A;
  const char* Bg = (const char*)B;
  long aOff[CA]; int aL[CA];
  #pragma unroll
  for (int j = 0; j < CA; j++){
    int i = (w*CA + j)*64 + lane;
    int r = i >> 3, g = (i & 7) ^ (r & 7);
    aOff[j] = ((long)(m0 + r)*K + g*8)*2;
    aL[j] = (w*CA + j)*1024;
  }
  long bOff[CB]; int bL[CB];
  #pragma unroll
  for (int j = 0; j < CB; j++){
    int i = (w*CB + j)*64 + lane;
    int r = i >> 3, g = (i & 7) ^ (r & 7);
    bOff[j] = ((long)(n0 + r)*K + g*8)*2;
    bL[j] = (w*CB + j)*1024;
  }

  const int NKI = K >> 6;
  #pragma unroll
  for (int j = 0; j < CA; j++) gload16(Ag + aOff[j], (char*)As[0] + aL[j]);
  #pragma unroll
  for (int j = 0; j < CB; j++) gload16(Bg + bOff[j], (char*)Bs[0] + bL[j]);
  asm volatile("s_waitcnt vmcnt(0)" ::: "memory");
  __syncthreads();

  for (int ki = 0; ki < NKI; ki++){
    int cur = ki & 1;
    if (ki + 1 < NKI){
      long kb = (long)(ki + 1)*128;
      #pragma unroll
      for (int j = 0; j < CA; j++) gload16(Ag + aOff[j] + kb, (char*)As[cur^1] + aL[j]);
      #pragma unroll
      for (int j = 0; j < CB; j++) gload16(Bg + bOff[j] + kb, (char*)Bs[cur^1] + bL[j]);
    }
    const unsigned short* Ac = As[cur];
    const unsigned short* Bc = Bs[cur];
    #pragma unroll
    for (int ks = 0; ks < 2; ks++){
      short8 af[MI], bfr[NI];
      #pragma unroll
      for (int mi = 0; mi < MI; mi++){
        int r = wm + mi*16 + l16;
        int pos = ((ks << 2) + quad) ^ (r & 7);
        af[mi] = *(const short8*)&Ac[r*64 + pos*8];
      }
      #pragma unroll
      for (int ni = 0; ni < NI; ni++){
        int r = wn + ni*16 + l16;
        int pos = ((ks << 2) + quad) ^ (r & 7);
        bfr[ni] = *(const short8*)&Bc[r*64 + pos*8];
      }
      #pragma unroll
      for (int mi = 0; mi < MI; mi++)
        #pragma unroll
        for (int ni = 0; ni < NI; ni++)
          acc[mi][ni] = __builtin_amdgcn_mfma_f32_16x16x32_bf16(af[mi], bfr[ni], acc[mi][ni], 0, 0, 0);
    }
    asm volatile("s_waitcnt vmcnt(0)" ::: "memory");
    __syncthreads();
  }
  #pragma unroll
  for (int mi = 0; mi < MI; mi++)
    #pragma unroll
    for (int ni = 0; ni < NI; ni++){
      int col = n0 + wn + ni*16 + l16;
      if (col >= N) continue;
      float bv = bias ? bias[col] : 0.f;
      #pragma unroll
      for (int rr = 0; rr < 4; rr++){
        int row = m0 + wm + mi*16 + (quad << 2) + rr;
        float v = acc[mi][ni][rr] + bv;
        if (rowscale) v *= rsqrtf(rowscale[row]*(1.f/(float)DINNER) + 1e-5f);
        long idx = (long)row*N + col;
        if (outMode == 2 || (outMode == 1 && f)) ((unsigned short*)C)[idx] = f2b(v);
        else                                     ((float*)C)[idx] = v;
      }
    }
}

// conv+silu for the shared B/C channels (256 of 1280, bf16 in/out) + dt softplus.
__global__ __launch_bounds__(256) void k_conv_dt(
    const unsigned short* __restrict__ zx, const float* __restrict__ cw, const float* __restrict__ cb,
    const float* __restrict__ dtb, unsigned short* __restrict__ xc, float* __restrict__ dt)
{
  int r = blockIdx.x; int b = r >> 9, l = r & 511;
  int t = threadIdx.x;
  {
    int ch = 1024 + t;                       // channel in [1024,1280)
    float s = cb[ch];
    #pragma unroll
    for (int k = 0; k < 4; k++){
      int pos = l - 3 + k;
      if (pos >= 0)
        s = fmaf(b2f(zx[(long)(b*L_SEQ + pos)*DINPROJ + 2048 + t]), cw[ch*4 + k], s);
    }
    xc[(long)r*256 + t] = f2b(s / (1.f + __expf(-s)));   // silu, bf16
  }
  if (t < NHEADSM){
    float v = b2f(zx[(long)r*DINPROJ + DINNER + CONVD + t]) + dtb[t];
    dt[r*NHEADSM + t] = (v > 20.f) ? v : log1pf(__expf(v));  // softplus
  }
}

// ================= chunked SSD scan (MFMA), x-conv fused =================
// ZX/XC/Y/S all bf16 (R15/R17/R21 verified).
__global__ __launch_bounds__(256) void k_chunk1(
    const unsigned short* __restrict__ zx, const unsigned short* __restrict__ xc,
    const float* __restrict__ dtbuf,
    const float* __restrict__ alog, const float* __restrict__ dvec,
    const float* __restrict__ cw, const float* __restrict__ cb,
    unsigned short* __restrict__ S, float* __restrict__ LAb,
    unsigned short* __restrict__ y)
{
  int c = blockIdx.x, h = blockIdx.y, b = blockIdx.z;
  int t = threadIdx.x, w = t >> 6, lane = t & 63;
  int quad = lane >> 4, l16 = lane & 15;
  int l0 = c*QCH;
  __shared__ unsigned short XT[64*40];    // XT[p][j] = X[j][p]
  __shared__ union {                      // time-multiplexed
    float xs[35*64];                      // x conv input slab (f32 in LDS)
    unsigned short BTc[128*40];           // BTc[n][j] = coef[j]*B[j][n]
  } U;
  __shared__ unsigned short Bb[32*136];   // B[j][n]
  __shared__ unsigned short Cb[32*136];   // C[i][n]
  __shared__ unsigned short Gb[32*40];    // G[i][j]
  __shared__ float dtl[32], lal[32], coef[32];
  float A  = -__expf(alog[h]);
  float Dv = dvec[h];

  // stage raw x conv input: rows l0-3..l0+31, zx cols 1024+h*64 .. +64
  for (int idx = t; idx < 35*64; idx += 256){
    int jr = idx >> 6, cc = idx & 63;
    int l = l0 - 3 + jr;
    U.xs[idx] = (l >= 0) ? b2f(zx[(long)(b*L_SEQ + l)*DINPROJ + 1024 + h*64 + cc]) : 0.f;
  }
  // B/C (conv'd by k_conv_dt, bf16 [r][256]) -> regs (raw ushort)
  unsigned short bu[16], cu[16];
  #pragma unroll
  for (int k = 0; k < 16; k++){
    int idx = t + k*256; int j = idx >> 7, n = idx & 127;
    long rb = (long)(b*L_SEQ + l0 + j)*256;
    bu[k] = xc[rb + n];
    cu[k] = xc[rb + 128 + n];
  }
  // lane-parallel inclusive prefix over dt
  if (t < 32){
    float d = dtbuf[(b*L_SEQ + l0 + t)*NHEADSM + h];
    dtl[t] = d;
    float s = d;
    #pragma unroll
    for (int o = 1; o < 32; o <<= 1){
      float u = __shfl_up(s, o, 32);
      if (t >= o) s += u;
    }
    float la = s * A;
    lal[t] = la;
    float tot = __shfl(s, 31, 32) * A;
    coef[t] = __expf(tot - la) * d;
    LAb[(b*NHEADSM + h)*L_SEQ + l0 + t] = la;
  }
  __syncthreads();     // xs staged, coef ready
  // conv+silu for x (identical tap order/padding semantics to reference)
  float xv[8];
  #pragma unroll
  for (int k = 0; k < 8; k++){
    int idx = t + k*256; int j = idx >> 6, p = idx & 63;
    int ch = h*64 + p;
    float s0 = cb[ch];
    #pragma unroll
    for (int kk = 0; kk < 4; kk++)
      s0 = fmaf(U.xs[(j + kk)*64 + p], cw[ch*4 + kk], s0);
    xv[k] = s0 / (1.f + __expf(-s0));
  }
  __syncthreads();     // xs dead; BTc may be written
  #pragma unroll
  for (int k = 0; k < 8; k++){
    int idx = t + k*256; int j = idx >> 6, p = idx & 63;
    XT[p*40 + j] = f2b(xv[k]);
  }
  #pragma unroll
  for (int k = 0; k < 16; k++){
    int idx = t + k*256; int j = idx >> 7, n = idx & 127;
    Bb[j*136 + n] = bu[k];
    Cb[j*136 + n] = cu[k];
    U.BTc[n*40 + j] = f2b(b2f(bu[k]) * coef[j]);
  }
  __syncthreads();

  short8 afS = *(const short8*)&XT[(w*16 + l16)*40 + quad*8];
  floatx4 accS[8];
  #pragma unroll
  for (int nb = 0; nb < 8; nb++){
    short8 bfS = *(const short8*)&U.BTc[(nb*16 + l16)*40 + quad*8];
    accS[nb] = __builtin_amdgcn_mfma_f32_16x16x32_bf16(afS, bfS, (floatx4){0.f,0.f,0.f,0.f}, 0, 0, 0);
  }
  int ti = w & 1, tj = w >> 1;
  floatx4 accG = (floatx4){0.f,0.f,0.f,0.f};
  #pragma unroll
  for (int ks = 0; ks < 4; ks++){
    short8 ga = *(const short8*)&Cb[(ti*16 + l16)*136 + ks*32 + quad*8];
    short8 gb = *(const short8*)&Bb[(tj*16 + l16)*136 + ks*32 + quad*8];
    accG = __builtin_amdgcn_mfma_f32_16x16x32_bf16(ga, gb, accG, 0, 0, 0);
  }
  long sb = ((long)((b*NHEADSM + h)*NCH + c))*8192;
  #pragma unroll
  for (int nb = 0; nb < 8; nb++)
    #pragma unroll
    for (int rr = 0; rr < 4; rr++)
      S[sb + (w*16 + quad*4 + rr)*128 + nb*16 + l16] = f2b(accS[nb][rr]);
  #pragma unroll
  for (int rr = 0; rr < 4; rr++){
    int i = ti*16 + quad*4 + rr, j = tj*16 + l16;
    float g = (j <= i) ? __expf(lal[i] - lal[j]) * dtl[j] * accG[rr] : 0.f;
    Gb[i*40 + j] = f2b(g);
  }
  __syncthreads();
  short8 ag = *(const short8*)&Gb[(ti*16 + l16)*40 + quad*8];
  #pragma unroll
  for (int s = 0; s < 2; s++){
    int pb = (w >> 1)*2 + s;
    short8 bx = *(const short8*)&XT[(pb*16 + l16)*40 + quad*8];
    floatx4 accY = __builtin_amdgcn_mfma_f32_16x16x32_bf16(ag, bx, (floatx4){0.f,0.f,0.f,0.f}, 0, 0, 0);
    #pragma unroll
    for (int rr = 0; rr < 4; rr++){
      int i = ti*16 + quad*4 + rr, p = pb*16 + l16;
      float xval = b2f(XT[p*40 + i]);
      y[(long)(b*L_SEQ + l0 + i)*DINNER + h*64 + p] = f2b(fmaf(Dv, xval, accY[rr]));
    }
  }
}

// chunk2: state propagation IN-PLACE over bf16 S (scan carried in f32 regs)
// + zero the SS accumulator.
__global__ __launch_bounds__(256) void k_chunk2(
    unsigned short* __restrict__ S, const float* __restrict__ LAb, float* __restrict__ SS)
{
  if (threadIdx.x == 0) SS[blockIdx.x] = 0.f;
  int bh = blockIdx.x >> 5;
  int e = ((blockIdx.x & 31) << 8) + threadIdx.x;
  long base = (long)bh*NCH*8192 + e;
  int laBase = bh*L_SEQ;
  float lam[NCH];
  #pragma unroll
  for (int c = 0; c < NCH; c++) lam[c] = __expf(LAb[laBase + c*QCH + QCH - 1]);
  float hr = 0.f;
  #pragma unroll
  for (int c = 0; c < NCH; c++){
    long off = base + (long)c*8192;
    float sv = b2f(S[off]);
    S[off] = f2b(hr);
    hr = fmaf(hr, lam[c], sv);
  }
}

// chunk3: yfin = b2f(y) + exp(la_i)*C.H^T with single-bf16 H;
// g = yfin*silu(b2f(z)) -> Ybf once; per-row sum(g^2) atomically into SS.
__global__ __launch_bounds__(256) void k_chunk3(
    const unsigned short* __restrict__ xc, const unsigned short* __restrict__ H,
    const float* __restrict__ LAb, const unsigned short* __restrict__ y,
    const unsigned short* __restrict__ zx, unsigned short* __restrict__ ybf,
    float* __restrict__ SS)
{
  int c = blockIdx.x, h = blockIdx.y, b = blockIdx.z;
  int t = threadIdx.x, w = t >> 6, lane = t & 63;
  int quad = lane >> 4, l16 = lane & 15;
  int l0 = c*QCH;
  __shared__ unsigned short Cb[32*136];
  __shared__ unsigned short Hb[64*136];
  __shared__ float el[32];
  if (t < 32) el[t] = __expf(LAb[(b*NHEADSM + h)*L_SEQ + l0 + t]);
  #pragma unroll
  for (int k = 0; k < 16; k++){
    int idx = t + k*256; int j = idx >> 7, n = idx & 127;
    Cb[j*136 + n] = xc[(long)(b*L_SEQ + l0 + j)*256 + 128 + n];
  }
  long hb = ((long)((b*NHEADSM + h)*NCH + c))*8192;
  #pragma unroll
  for (int k = 0; k < 32; k++){
    int idx = t + k*256; int p = idx >> 7, n = idx & 127;
    Hb[p*136 + n] = H[hb + idx];
  }
  __syncthreads();
  int ti = w & 1;
  float gsq[4] = {0.f, 0.f, 0.f, 0.f};
  #pragma unroll
  for (int s = 0; s < 2; s++){
    int pb = (w >> 1)*2 + s;
    floatx4 acc = (floatx4){0.f,0.f,0.f,0.f};
    #pragma unroll
    for (int ks = 0; ks < 4; ks++){
      short8 a  = *(const short8*)&Cb[(ti*16 + l16)*136 + ks*32 + quad*8];
      short8 hf = *(const short8*)&Hb[(pb*16 + l16)*136 + ks*32 + quad*8];
      acc = __builtin_amdgcn_mfma_f32_16x16x32_bf16(a, hf, acc, 0, 0, 0);
    }
    #pragma unroll
    for (int rr = 0; rr < 4; rr++){
      int i = ti*16 + quad*4 + rr, p = pb*16 + l16;
      long row = (long)(b*L_SEQ + l0 + i);
      long yb = row*DINNER + h*64 + p;
      float yfin = fmaf(el[i], acc[rr], b2f(y[yb]));
      float z = b2f(zx[row*DINPROJ + h*64 + p]);
      float gz = z / (1.f + __expf(-z));
      float g = yfin * gz;
      ybf[yb] = f2b(g);
      gsq[rr] = fmaf(g, g, gsq[rr]);
    }
  }
  // reduce over the 16 lanes sharing each row (same quad, varying l16)
  #pragma unroll
  for (int rr = 0; rr < 4; rr++){
    float v = gsq[rr];
    v += __shfl_xor(v, 1);
    v += __shfl_xor(v, 2);
    v += __shfl_xor(v, 4);
    v += __shfl_xor(v, 8);
    if (l16 == 0)
      atomicAdd(&SS[b*L_SEQ + l0 + ti*16 + quad*4 + rr], v);
  }
}

// add + layernorm; o (out_proj output) f32 (R21 best-measured config).
__global__ __launch_bounds__(256) void k_add_ln(
    float* __restrict__ x, const float* __restrict__ o,
    const float* __restrict__ lw, const float* __restrict__ lb,
    unsigned short* __restrict__ xbf)
{
  int r = blockIdx.x, t = threadIdx.x;
  float v[2]; float sm = 0.f;
  #pragma unroll
  for (int i = 0; i < 2; i++){ int c = t + i*256; v[i] = x[(long)r*DMODEL + c] + o[(long)r*DMODEL + c]; sm += v[i]; }
  #pragma unroll
  for (int off = 1; off < 64; off <<= 1) sm += __shfl_xor(sm, off);
  __shared__ float red[4]; __shared__ float red2[4];
  int w = t >> 6, lane = t & 63;
  if (lane == 0) red[w] = sm;
  __syncthreads();
  float mu = (red[0] + red[1] + red[2] + red[3]) / (float)DMODEL;
  float var = 0.f;
  #pragma unroll
  for (int i = 0; i < 2; i++){ v[i] -= mu; var = fmaf(v[i], v[i], var); }
  #pragma unroll
  for (int off = 1; off < 64; off <<= 1) var += __shfl_xor(var, off);
  if (lane == 0) red2[w] = var;
  __syncthreads();
  float vv = (red2[0] + red2[1] + red2[2] + red2[3]) / (float)DMODEL;
  float sc = rsqrtf(vv + 1e-5f);
  #pragma unroll
  for (int i = 0; i < 2; i++){
    int c = t + i*256;
    float ov = v[i]*sc*lw[c] + lb[c];
    x[(long)r*DMODEL + c] = ov;
    xbf[(long)r*DMODEL + c] = f2b(ov);
  }
}

extern "C" void kernel_launch(void* const* d_in, const int* in_sizes, int n_in,
                              void* d_out, int out_size, void* d_ws, size_t ws_size,
                              hipStream_t stream)
{
  const int* tokens = (const int*)d_in[0];
  const void* emb = d_in[1];
  int* flag = (int*)d_ws;
  float* ws = (float*)((char*)d_ws + 256);

  k_detect<<<1, 256, 0, stream>>>((const unsigned*)emb, flag);

  ConvArgs ca;
  const int sizes[9] = {10240, 2560, 32, 32, 32, 2048, 1024, 1024, 1000};
  const int idxs[9]  = {3, 4, 5, 6, 7, 8, 10, 11, 13};
  int off = 0;
  for (int s = 0; s < 9; s++){ ca.src[s] = d_in[idxs[s]]; ca.off[s] = off; off += sizes[s]; }
  ca.off[9] = off;

  float* X  = ws + O_X;
  unsigned short* ZXu = (unsigned short*)(ws + O_ZX);
  unsigned short* XCu = (unsigned short*)(ws + O_XC);
  float* DT = ws + O_DT;
  unsigned short* Y16 = (unsigned short*)(ws + O_Y);
  float* Ob = ws + O_O;
  float* LA = ws + O_LA;
  float* SSb= ws + O_SS;
  unsigned short* S16 = (unsigned short*)(ws + O_S);
  unsigned short* ub  = (unsigned short*)(ws + O_UB);
  unsigned short* WiB = ub + U_WI;
  unsigned short* WoB = ub + U_WO;
  unsigned short* WhB = ub + U_WH;
  unsigned short* Xbf = ub + U_XBF;
  unsigned short* Ybf = ub + U_YBF;

  k_prep<<<71 + NPREPW + NROWS, 256, 0, stream>>>(
      ca, d_in[2], d_in[9], d_in[12], d_in[8], tokens, emb, flag,
      ws, WiB, WoB, WhB, X, Xbf);

  for (int layer = 0; layer < 2; layer++){
    // in_proj: ZX output stored bf16 (outMode=2)
    k_mfma_nt<32,64><<<dim3(WI_PAD/64, NROWS/32), 256, 0, stream>>>(
        Xbf, WiB + (long)layer*WI_PAD*DMODEL, (void*)ZXu,
        NROWS, DINPROJ, DMODEL, (const float*)nullptr, (const float*)nullptr, flag, 2);
    k_conv_dt<<<NROWS, 256, 0, stream>>>(
        ZXu, ws + W_CONVW + layer*5120, ws + W_CONVB + layer*1280, ws + W_DTB + layer*16, XCu, DT);
    k_chunk1<<<dim3(NCH, NHEADSM, BATCH), 256, 0, stream>>>(
        ZXu, XCu, DT, ws + W_ALOG + layer*16, ws + W_DD + layer*16,
        ws + W_CONVW + layer*5120, ws + W_CONVB + layer*1280, S16, LA, Y16);
    k_chunk2<<<1024, 256, 0, stream>>>(S16, LA, SSb);
    k_chunk3<<<dim3(NCH, NHEADSM, BATCH), 256, 0, stream>>>(
        XCu, S16, LA, Y16, ZXu, Ybf, SSb);
    // out_proj: f32 Ob, rms row-scale in epilogue
    k_mfma_nt<32,32><<<dim3(DMODEL/32, NROWS/32), 256, 0, stream>>>(
        Ybf, WoB + (long)layer*DMODEL*DINNER, (void*)Ob,
        NROWS, DMODEL, DINNER, (const float*)nullptr, SSb, flag, 0);
    k_add_ln<<<NROWS, 256, 0, stream>>>(X, Ob, ws + W_LNW + layer*512, ws + W_LNB + layer*512, Xbf);
  }

  k_mfma_nt<32,64><<<dim3(WH_PAD/64, NROWS/32), 256, 0, stream>>>(
      Xbf, WhB, d_out, NROWS, 1000, DMODEL, ws + W_HEADB, (const float*)nullptr, flag, 1);
}